// Round 6
// baseline (409.996 us; speedup 1.0000x reference)
//
#include <hip/hip_runtime.h>

#define N_NODES 50000
#define N_EDGES 800000
#define D 64          // D_IN == D_OUT
#define ED 32         // EDGE_DIM
#define BN_EPS 1e-5f

// ---- workspace layout (32-bit word indices) -------------------------------
#define WS_SUMS     0
#define WS_SUMSQ    64
#define WS_PART     128                       // 64 ints: scan partials
#define WS_DEG      256
#define WS_ZERO_END (WS_DEG + N_NODES)        // memset [0, here)  (~201 KB)
#define WS_OFF      (WS_DEG + N_NODES)        // 50256
#define WS_CURSOR   (WS_OFF + N_NODES + 4)    // 100260
#define WS_SRC      (WS_CURSOR + N_NODES)     // 150260
#define WS_EAB      (WS_SRC + N_EDGES)        // 950260   (bf16 ea rows, 64B each)
#define WS_H        (WS_EAB + 16 * N_EDGES)   // 13750260
#define WS_XB       (WS_H + N_NODES * D)      // 16950260 (bf16 x, ushort[N*D])
#define WS_FAST_WORDS  (WS_H + N_NODES * D)             // R4 path: 67.8 MB
#define WS_FAST2_WORDS (WS_XB + N_NODES * D / 2)        // +xb:    74.2 MB

#define SCAN_BLOCKS 50   // 50 x 1000 = N_NODES exactly

__device__ __forceinline__ unsigned int bf16r(float f) {
    unsigned int u = __float_as_uint(f);
    return (u + 0x7fffu + ((u >> 16) & 1u)) >> 16;     // round-to-nearest-even
}
__device__ __forceinline__ unsigned int pack2(float lo, float hi) {
    return bf16r(lo) | (bf16r(hi) << 16);
}
__device__ __forceinline__ float b2f(unsigned int u) {
    return __uint_as_float(u << 16);
}

// ---------------------------------------------------------------------------
// degree histogram (int atomics) + optional x -> bf16 conversion (sequential)
__global__ __launch_bounds__(256) void count_convert_kernel(
    const int* __restrict__ dst, int* __restrict__ deg,
    const float* __restrict__ x, unsigned int* __restrict__ xb /*may be null*/)
{
    const int g = blockIdx.x * 256 + threadIdx.x;
    const int stride = gridDim.x * 256;
    if (g < N_EDGES / 4) {
        int4 d = ((const int4*)dst)[g];
        atomicAdd(&deg[d.x], 1);
        atomicAdd(&deg[d.y], 1);
        atomicAdd(&deg[d.z], 1);
        atomicAdd(&deg[d.w], 1);
    }
    if (xb) {
        for (int i = g; i < N_NODES * D / 4; i += stride) {
            float4 v = ((const float4*)x)[i];
            ((uint2*)xb)[i] = make_uint2(pack2(v.x, v.y), pack2(v.z, v.w));
        }
    }
}

// per-block partial sums over 1000 ints (coalesced int4)
__global__ __launch_bounds__(256) void scan_partial_kernel(
    const int* __restrict__ deg, int* __restrict__ partial)
{
    __shared__ int sR[256];
    const int t = threadIdx.x;
    const int base = blockIdx.x * 1000;
    int local = 0;
    if (t < 250) {
        int4 d = ((const int4*)(deg + base))[t];
        local = d.x + d.y + d.z + d.w;
    }
    sR[t] = local;
    __syncthreads();
    for (int o = 128; o > 0; o >>= 1) {
        if (t < o) sR[t] += sR[t + o];
        __syncthreads();
    }
    if (t == 0) partial[blockIdx.x] = sR[0];
}

// block-local scan + in-kernel top scan of the 50 partials; writes off & cursor
__global__ __launch_bounds__(256) void scan_write_kernel(
    const int* __restrict__ deg, const int* __restrict__ partial,
    int* __restrict__ off, int* __restrict__ cursor)
{
    __shared__ int sS[256];
    __shared__ int sTop;
    const int t = threadIdx.x;
    if (t < 64) {                       // wave 0: exclusive scan of partials
        int v = (t < SCAN_BLOCKS) ? partial[t] : 0;
        int inc = v;
        for (int o = 1; o < 64; o <<= 1) {
            int u = __shfl_up(inc, o);
            if (t >= o) inc += u;
        }
        if (t == blockIdx.x) sTop = inc - v;
    }
    const int base = blockIdx.x * 1000;
    int4 d = make_int4(0, 0, 0, 0);
    int local = 0;
    if (t < 250) {
        d = ((const int4*)(deg + base))[t];
        local = d.x + d.y + d.z + d.w;
    }
    sS[t] = local;
    __syncthreads();
    for (int o = 1; o < 256; o <<= 1) {
        int v = sS[t];
        int add = (t >= o) ? sS[t - o] : 0;
        __syncthreads();
        sS[t] = v + add;
        __syncthreads();
    }
    if (t < 250) {
        int p = sTop + sS[t] - local;   // exclusive prefix
        int4 o4 = make_int4(p, p + d.x, p + d.x + d.y, p + d.x + d.y + d.z);
        ((int4*)(off + base))[t] = o4;
        ((int4*)(cursor + base))[t] = o4;
    }
    if (blockIdx.x == 0 && t == 0) off[N_NODES] = N_EDGES;
}

// ---------------------------------------------------------------------------
// permute ea (f32, edge order, sequential read) -> bf16x2 rows in dst-sorted
// order (random 64B writes). 8 lanes per edge; E%8==0.
__global__ __launch_bounds__(256) void permute_kernel(
    const int* __restrict__ ei, const float* __restrict__ ea,
    int* __restrict__ cursor, int* __restrict__ sorted_src,
    unsigned int* __restrict__ eab)
{
    const int tid = threadIdx.x;
    const int lane = tid & 63;
    const int g = lane >> 3, sub = lane & 7;
    const int wv = blockIdx.x * 4 + (tid >> 6);
    const int nwv = gridDim.x * 4;
    for (int e0 = wv * 8; e0 < N_EDGES; e0 += nwv * 8) {
        const int e = e0 + g;
        const float4 v = ((const float4*)ea)[(size_t)e * 8 + sub];  // 1KB/wave seq
        int pos = 0;
        if (sub == 0) {
            const int src = ei[e];
            const int dst = ei[N_EDGES + e];
            pos = atomicAdd(&cursor[dst], 1);
            sorted_src[pos] = src;
        }
        pos = __shfl(pos, g * 8);
        uint2 p;
        p.x = pack2(v.x, v.y);          // uint j holds features (2j, 2j+1)
        p.y = pack2(v.z, v.w);
        ((uint2*)eab)[(size_t)pos * 8 + sub] = p;   // 64B row, random
    }
}

// ---------------------------------------------------------------------------
// FAST2: per-node aggregation with bf16 x gathers (128B/row) + MLP1 + BN stats
__global__ __launch_bounds__(256) void agg_mlp1_fast2(
    const unsigned short* __restrict__ xb, const float* __restrict__ x,
    const unsigned int* __restrict__ eab,
    const float* __restrict__ We, const float* __restrict__ be,
    const float* __restrict__ W1, const float* __restrict__ b1,
    const int* __restrict__ off, const int* __restrict__ sorted_src,
    float* __restrict__ h, float* __restrict__ sums, float* __restrict__ sumsq)
{
    __shared__ float sWe[ED][D];     // 8 KB
    __shared__ float sW1[D][D];      // 16 KB
    __shared__ float sRed[2][4][D];  // 2 KB

    const int tid = threadIdx.x;
    for (int i = tid; i < ED * D; i += 256) sWe[i >> 6][i & 63] = We[i];
    for (int i = tid; i < D * D; i += 256) sW1[i >> 6][i & 63] = W1[i];
    const int f = tid & 63;
    const int w = tid >> 6;
    const float be_f = be[f], b1_f = b1[f];
    float psum = 0.f, psq = 0.f;
    __syncthreads();

    const int gstride = gridDim.x * 4;
    for (int node0 = blockIdx.x * 4; node0 < N_NODES; node0 += gstride) {
        const int node = node0 + w;    // wave-uniform
        if (node < N_NODES) {
            const int start = off[node], end = off[node + 1];
            const int n = end - start;
            const int* sp = sorted_src + start;
            const unsigned int* ep = eab + (size_t)start * 16;
            float s0 = 0.f, s1 = 0.f, s2 = 0.f, s3 = 0.f, eax = 0.f, eay = 0.f;
            int it = 0;
            int a0 = 0, a1 = 0, a2 = 0, a3 = 0;
            unsigned int ue = 0;
            if (n >= 4) {
                a0 = sp[0]; a1 = sp[1]; a2 = sp[2]; a3 = sp[3];
                ue = ep[f];                    // rows 0..3: lane = row f>>4, pair f&15
            }
            for (; it + 8 <= n; it += 4) {     // pipelined
                const int n0 = sp[it + 4], n1 = sp[it + 5];
                const int n2 = sp[it + 6], n3 = sp[it + 7];
                const unsigned int un = ep[(it + 4) * 16 + f];
                s0 += b2f(xb[(size_t)a0 * D + f]);
                s1 += b2f(xb[(size_t)a1 * D + f]);
                s2 += b2f(xb[(size_t)a2 * D + f]);
                s3 += b2f(xb[(size_t)a3 * D + f]);
                eax += __uint_as_float(ue << 16);
                eay += __uint_as_float(ue & 0xffff0000u);
                a0 = n0; a1 = n1; a2 = n2; a3 = n3; ue = un;
            }
            if (it + 4 <= n) {
                s0 += b2f(xb[(size_t)a0 * D + f]);
                s1 += b2f(xb[(size_t)a1 * D + f]);
                s2 += b2f(xb[(size_t)a2 * D + f]);
                s3 += b2f(xb[(size_t)a3 * D + f]);
                eax += __uint_as_float(ue << 16);
                eay += __uint_as_float(ue & 0xffff0000u);
                it += 4;
            }
            if (it < n) {                      // tail: 1..3 rows
                if ((f >> 4) < (n - it)) {
                    const unsigned int ut = ep[it * 16 + f];
                    eax += __uint_as_float(ut << 16);
                    eay += __uint_as_float(ut & 0xffff0000u);
                }
                for (; it < n; ++it) s0 += b2f(xb[(size_t)sp[it] * D + f]);
            }
            eax += __shfl_xor(eax, 16); eax += __shfl_xor(eax, 32);
            eay += __shfl_xor(eay, 16); eay += __shfl_xor(eay, 32);
            float val = (s0 + s1) + (s2 + s3) + x[(size_t)node * D + f]
                      + (float)n * be_f;
            #pragma unroll
            for (int k = 0; k < ED; ++k) {
                const float a = (k & 1) ? eay : eax;   // lane k>>1 holds pair k>>1
                val += __shfl(a, k >> 1) * sWe[k][f];
            }
            float hacc = b1_f;
            #pragma unroll
            for (int k = 0; k < D; ++k) hacc += __shfl(val, k) * sW1[k][f];
            h[(size_t)node * D + f] = hacc;
            psum += hacc;
            psq += hacc * hacc;
        }
    }
    sRed[0][w][f] = psum;
    sRed[1][w][f] = psq;
    __syncthreads();
    if (w == 0) {
        const float s = sRed[0][0][f] + sRed[0][1][f] + sRed[0][2][f] + sRed[0][3][f];
        const float q = sRed[1][0][f] + sRed[1][1][f] + sRed[1][2][f] + sRed[1][3][f];
        unsafeAtomicAdd(&sums[f], s);
        unsafeAtomicAdd(&sumsq[f], q);
    }
}

// FAST (R4 fallback, f32 x gathers) — used when ws can't hold xb
__global__ __launch_bounds__(256) void agg_mlp1_fast(
    const float* __restrict__ x, const unsigned int* __restrict__ eab,
    const float* __restrict__ We, const float* __restrict__ be,
    const float* __restrict__ W1, const float* __restrict__ b1,
    const int* __restrict__ off, const int* __restrict__ sorted_src,
    float* __restrict__ h, float* __restrict__ sums, float* __restrict__ sumsq)
{
    __shared__ float sWe[ED][D];
    __shared__ float sW1[D][D];
    __shared__ float sRed[2][4][D];

    const int tid = threadIdx.x;
    for (int i = tid; i < ED * D; i += 256) sWe[i >> 6][i & 63] = We[i];
    for (int i = tid; i < D * D; i += 256) sW1[i >> 6][i & 63] = W1[i];
    const int f = tid & 63;
    const int w = tid >> 6;
    const float be_f = be[f], b1_f = b1[f];
    float psum = 0.f, psq = 0.f;
    __syncthreads();

    const int gstride = gridDim.x * 4;
    for (int node0 = blockIdx.x * 4; node0 < N_NODES; node0 += gstride) {
        const int node = node0 + w;
        if (node < N_NODES) {
            const int start = off[node], end = off[node + 1];
            const int n = end - start;
            const int* sp = sorted_src + start;
            const unsigned int* ep = eab + (size_t)start * 16;
            float s0 = 0.f, s1 = 0.f, s2 = 0.f, s3 = 0.f, eax = 0.f, eay = 0.f;
            int it = 0;
            int a0 = 0, a1 = 0, a2 = 0, a3 = 0;
            unsigned int ue = 0;
            if (n >= 4) {
                a0 = sp[0]; a1 = sp[1]; a2 = sp[2]; a3 = sp[3];
                ue = ep[f];
            }
            for (; it + 8 <= n; it += 4) {
                const int n0 = sp[it + 4], n1 = sp[it + 5];
                const int n2 = sp[it + 6], n3 = sp[it + 7];
                const unsigned int un = ep[(it + 4) * 16 + f];
                s0 += x[(size_t)a0 * D + f];
                s1 += x[(size_t)a1 * D + f];
                s2 += x[(size_t)a2 * D + f];
                s3 += x[(size_t)a3 * D + f];
                eax += __uint_as_float(ue << 16);
                eay += __uint_as_float(ue & 0xffff0000u);
                a0 = n0; a1 = n1; a2 = n2; a3 = n3; ue = un;
            }
            if (it + 4 <= n) {
                s0 += x[(size_t)a0 * D + f];
                s1 += x[(size_t)a1 * D + f];
                s2 += x[(size_t)a2 * D + f];
                s3 += x[(size_t)a3 * D + f];
                eax += __uint_as_float(ue << 16);
                eay += __uint_as_float(ue & 0xffff0000u);
                it += 4;
            }
            if (it < n) {
                if ((f >> 4) < (n - it)) {
                    const unsigned int ut = ep[it * 16 + f];
                    eax += __uint_as_float(ut << 16);
                    eay += __uint_as_float(ut & 0xffff0000u);
                }
                for (; it < n; ++it) s0 += x[(size_t)sp[it] * D + f];
            }
            eax += __shfl_xor(eax, 16); eax += __shfl_xor(eax, 32);
            eay += __shfl_xor(eay, 16); eay += __shfl_xor(eay, 32);
            float val = (s0 + s1) + (s2 + s3) + x[(size_t)node * D + f]
                      + (float)n * be_f;
            #pragma unroll
            for (int k = 0; k < ED; ++k) {
                const float a = (k & 1) ? eay : eax;
                val += __shfl(a, k >> 1) * sWe[k][f];
            }
            float hacc = b1_f;
            #pragma unroll
            for (int k = 0; k < D; ++k) hacc += __shfl(val, k) * sW1[k][f];
            h[(size_t)node * D + f] = hacc;
            psum += hacc;
            psq += hacc * hacc;
        }
    }
    sRed[0][w][f] = psum;
    sRed[1][w][f] = psq;
    __syncthreads();
    if (w == 0) {
        const float s = sRed[0][0][f] + sRed[0][1][f] + sRed[0][2][f] + sRed[0][3][f];
        const float q = sRed[1][0][f] + sRed[1][1][f] + sRed[1][2][f] + sRed[1][3][f];
        unsafeAtomicAdd(&sums[f], s);
        unsafeAtomicAdd(&sumsq[f], q);
    }
}

// ---------------------------------------------------------------------------
// MLP2 with BN stats finalized inline per block: out = relu(h*sc+sh) @ W2 + b2
__global__ __launch_bounds__(256) void mlp2_kernel(
    const float* __restrict__ h, const float* __restrict__ W2,
    const float* __restrict__ b2, const float* __restrict__ sums,
    const float* __restrict__ sumsq, const float* __restrict__ gamma,
    const float* __restrict__ beta, float* __restrict__ out)
{
    __shared__ float sW2[D][D];  // 16 KB
    const int tid = threadIdx.x;
    for (int i = tid; i < D * D; i += 256) sW2[i >> 6][i & 63] = W2[i];
    const int f = tid & 63;
    const int w = tid >> 6;
    const float inv_n = 1.0f / (float)N_NODES;
    const float mean = sums[f] * inv_n;
    const float var  = sumsq[f] * inv_n - mean * mean;   // biased, like jnp.var
    const float sc   = gamma[f] * rsqrtf(var + BN_EPS);
    const float sh   = beta[f] - mean * sc;
    const float b    = b2[f];
    __syncthreads();

    const int gstride = gridDim.x * 4;
    for (int node0 = blockIdx.x * 4; node0 < N_NODES; node0 += gstride) {
        const int node = node0 + w;
        if (node < N_NODES) {
            float v = h[(size_t)node * D + f] * sc + sh;
            v = v > 0.f ? v : 0.f;
            float acc = b;
            #pragma unroll
            for (int k = 0; k < D; ++k) acc += __shfl(v, k) * sW2[k][f];
            out[(size_t)node * D + f] = acc;
        }
    }
}

// ---------------------------------------------------------------------------
extern "C" void kernel_launch(void* const* d_in, const int* in_sizes, int n_in,
                              void* d_out, int out_size, void* d_ws, size_t ws_size,
                              hipStream_t stream) {
    const float* x     = (const float*)d_in[0];
    const int*   ei    = (const int*)  d_in[1];   // [2, E] int32
    const float* ea    = (const float*)d_in[2];
    const float* We    = (const float*)d_in[3];
    const float* be    = (const float*)d_in[4];
    const float* W1    = (const float*)d_in[5];
    const float* b1    = (const float*)d_in[6];
    const float* gamma = (const float*)d_in[7];
    const float* beta  = (const float*)d_in[8];
    const float* W2    = (const float*)d_in[9];
    const float* b2    = (const float*)d_in[10];

    float* ws      = (float*)d_ws;
    float* sums    = ws + WS_SUMS;
    float* sumsq   = ws + WS_SUMSQ;
    int*   partial = (int*)(ws + WS_PART);
    int*   deg     = (int*)(ws + WS_DEG);
    int*   off     = (int*)(ws + WS_OFF);
    int*   cursor  = (int*)(ws + WS_CURSOR);
    int*   ssrc    = (int*)(ws + WS_SRC);
    unsigned int* eab = (unsigned int*)(ws + WS_EAB);
    float* h       = ws + WS_H;
    unsigned int* xb = (unsigned int*)(ws + WS_XB);

    const bool fast2 = ws_size >= (size_t)WS_FAST2_WORDS * sizeof(float);

    hipMemsetAsync(ws, 0, (size_t)WS_ZERO_END * sizeof(float), stream);

    count_convert_kernel<<<784, 256, 0, stream>>>(ei + N_EDGES, deg, x,
                                                  fast2 ? xb : nullptr);
    scan_partial_kernel<<<SCAN_BLOCKS, 256, 0, stream>>>(deg, partial);
    scan_write_kernel  <<<SCAN_BLOCKS, 256, 0, stream>>>(deg, partial, off, cursor);
    permute_kernel     <<<2048, 256, 0, stream>>>(ei, ea, cursor, ssrc, eab);
    if (fast2) {
        agg_mlp1_fast2 <<<1536, 256, 0, stream>>>((const unsigned short*)xb, x, eab,
                                                  We, be, W1, b1, off, ssrc,
                                                  h, sums, sumsq);
    } else {
        agg_mlp1_fast  <<<1536, 256, 0, stream>>>(x, eab, We, be, W1, b1, off, ssrc,
                                                  h, sums, sumsq);
    }
    mlp2_kernel        <<<1024, 256, 0, stream>>>(h, W2, b2, sums, sumsq,
                                                  gamma, beta, (float*)d_out);
}